// Round 7
// baseline (3062.780 us; speedup 1.0000x reference)
//
#include <hip/hip_runtime.h>
#include <hip/hip_bf16.h>

#define H 500
#define D_IN 512
#define D_OUT 100
#define STEPS 49

typedef _Float16 h2_t __attribute__((ext_vector_type(2)));

#if defined(__has_builtin)
#if __has_builtin(__builtin_amdgcn_fdot2)
#define HAVE_FDOT2 1
#endif
#endif

__device__ __forceinline__ float fdot2f(h2_t a, h2_t b, float c) {
#ifdef HAVE_FDOT2
    return __builtin_amdgcn_fdot2(a, b, c, false);
#else
    return c + (float)a[0] * (float)b[0] + (float)a[1] * (float)b[1];
#endif
}
__device__ __forceinline__ h2_t bch2(unsigned u) { return __builtin_bit_cast(h2_t, u); }

__device__ __forceinline__ float tanh_fast(float x) {
    const float e = __expf(2.f * x);
    return 1.f - 2.f / (e + 1.f);
}

// ---------------- K01 fused.
// Blocks 0..62 (c = blockIdx.x): pack W_hh chunk c. Thread t packs cols
// 8c..8c+7 of rows 2t (-> blob_even[c*256+t]) and 2t+1 (-> blob_odd[c*256+t]),
// f32 -> f16 pairs, zero-padded past 500 (rows and cols).
// Blocks 63..187: xproj[t*512+r] = b_ih[r]+b_hh[r]+sum_d seq[t][d]*W_ih[r][d].
__global__ void k01_pack_xproj(const float* __restrict__ W_hh, const float* __restrict__ x,
                               const float* __restrict__ W_ih, const float* __restrict__ b_ih,
                               const float* __restrict__ b_hh,
                               uint4* __restrict__ blob_even, uint4* __restrict__ blob_odd,
                               float* __restrict__ xproj) {
    if (blockIdx.x < 63) {
        const int c = blockIdx.x;
        const int t = threadIdx.x;            // 0..255
        const int c0 = 8 * c;
#pragma unroll
        for (int par = 0; par < 2; par++) {
            const int row = 2 * t + par;
            _Float16 v[8];
#pragma unroll
            for (int e = 0; e < 8; e++) {
                const int col = c0 + e;
                v[e] = (row < H && col < H) ? (_Float16)W_hh[row * H + col] : (_Float16)0.f;
            }
            uint4 u;
            u.x = __builtin_bit_cast(unsigned, h2_t{v[0], v[1]});
            u.y = __builtin_bit_cast(unsigned, h2_t{v[2], v[3]});
            u.z = __builtin_bit_cast(unsigned, h2_t{v[4], v[5]});
            u.w = __builtin_bit_cast(unsigned, h2_t{v[6], v[7]});
            (par ? blob_odd : blob_even)[c * 256 + t] = u;
        }
    } else {
        const int wv = threadIdx.x >> 6, lane = threadIdx.x & 63;
        const int r = (blockIdx.x - 63) * 4 + wv;      // 0..499
        if (r >= H) return;
        float wr[8];
#pragma unroll
        for (int k = 0; k < 8; k++) wr[k] = W_ih[r * D_IN + k * 64 + lane];
        float p[STEPS];
#pragma unroll
        for (int t = 0; t < STEPS; t++) p[t] = 0.f;
#pragma unroll
        for (int k = 0; k < 8; k++) {
            const float* xr = x + (size_t)(k * 64 + lane) * STEPS;
#pragma unroll
            for (int t = 0; t < STEPS; t++) p[t] = fmaf(wr[k], xr[t], p[t]);
        }
#pragma unroll
        for (int t = 0; t < STEPS; t++) {
            float v = p[t];
            v += __shfl_xor(v, 32); v += __shfl_xor(v, 16); v += __shfl_xor(v, 8);
            v += __shfl_xor(v, 4);  v += __shfl_xor(v, 2);  v += __shfl_xor(v, 1);
            p[t] = v;
        }
        if (lane == 0) {
            const float b = b_ih[r] + b_hh[r];
            for (int t = 0; t < STEPS; t++) xproj[t * 512 + r] = p[t] + b;
        }
    }
}

// ---------------- K2: single-CU scan. 256 threads = 4 waves = 1 wave/SIMD ->
// 512 unified regs/wave. Weight residency via ALLOCATOR-MANAGED AGPR virtual
// registers ("=a"/"a" asm constraints): liveness tracked (no trampling, unlike
// physical aN names), opaque (no remat), both class caps satisfied
// (252 AGPR <= 256; ~170 arch VGPR <= 256) -> no spills.
// Thread tid: even row 2*tid entirely in AGPRs (63 uint4 chunks); odd row
// 2*tid+1: chunks 0..37 LDS-resident, chunks 38..62 in plain VGPR locals.
// h double-buffered f16[2][512] in LDS; ONE barrier per step; no reduction.
__global__ void __launch_bounds__(256, 1)
k2_scan(const float* __restrict__ hidden0,
        const uint4* __restrict__ blob_even, const uint4* __restrict__ blob_odd,
        const float* __restrict__ xproj, float* __restrict__ Hs) {
    __shared__ uint4 wlds[38 * 256];                 // 155648 B
    __shared__ __align__(16) _Float16 h16[2][512];   // 2048 B

    const int tid = threadIdx.x;                     // 0..255

    // ---- preload: even-row chunks 0..62 -> AGPR-class virtual regs ----
    unsigned wa[252];
#pragma unroll
    for (int c = 0; c < 63; c++) {
        const uint4 u = blob_even[c * 256 + tid];
        asm volatile("v_accvgpr_write_b32 %0, %1" : "=a"(wa[4 * c + 0]) : "v"(u.x));
        asm volatile("v_accvgpr_write_b32 %0, %1" : "=a"(wa[4 * c + 1]) : "v"(u.y));
        asm volatile("v_accvgpr_write_b32 %0, %1" : "=a"(wa[4 * c + 2]) : "v"(u.z));
        asm volatile("v_accvgpr_write_b32 %0, %1" : "=a"(wa[4 * c + 3]) : "v"(u.w));
    }
    // ---- preload: odd-row chunks 38..62 -> plain VGPR locals ----
    uint4 ov[25];
#pragma unroll
    for (int c = 0; c < 25; c++) ov[c] = blob_odd[(38 + c) * 256 + tid];
    // ---- preload: odd-row chunks 0..37 -> LDS ----
#pragma unroll
    for (int c = 0; c < 38; c++) wlds[c * 256 + tid] = blob_odd[c * 256 + tid];

    // ---- h0 ----
    {
        unsigned hp = 0u;
        if (tid < 250) {
            const float2 h0 = *(const float2*)(hidden0 + 2 * tid);
            hp = __builtin_bit_cast(unsigned, h2_t{(_Float16)h0.x, (_Float16)h0.y});
        }
        ((unsigned*)&h16[0][0])[tid] = hp;
    }
    __syncthreads();

#pragma unroll 1
    for (int t = 0; t < STEPS; ++t) {
        const uint4* hrd = (const uint4*)&h16[t & 1][0];
        float xp0 = 0.f, xp1 = 0.f;
        if (tid < 250) {
            const float2 xpv = *(const float2*)(xproj + t * 512 + 2 * tid);
            xp0 = xpv.x; xp1 = xpv.y;
        }
        float s0 = 0.f, s1 = 0.f, s2 = 0.f, s3 = 0.f;      // even row
        float o0 = 0.f, o1 = 0.f, o2 = 0.f, o3 = 0.f;      // odd row

        // chunks 0..37: even from AGPR, odd from LDS (shared hrd[c] broadcast)
#pragma unroll
        for (int c = 0; c < 38; c++) {
            const uint4 hb = hrd[c];
            unsigned w0, w1, w2, w3;
            asm volatile("v_accvgpr_read_b32 %0, %1" : "=v"(w0) : "a"(wa[4 * c + 0]));
            asm volatile("v_accvgpr_read_b32 %0, %1" : "=v"(w1) : "a"(wa[4 * c + 1]));
            asm volatile("v_accvgpr_read_b32 %0, %1" : "=v"(w2) : "a"(wa[4 * c + 2]));
            asm volatile("v_accvgpr_read_b32 %0, %1" : "=v"(w3) : "a"(wa[4 * c + 3]));
            s0 = fdot2f(bch2(w0), bch2(hb.x), s0);
            s1 = fdot2f(bch2(w1), bch2(hb.y), s1);
            s2 = fdot2f(bch2(w2), bch2(hb.z), s2);
            s3 = fdot2f(bch2(w3), bch2(hb.w), s3);
            const uint4 wv = wlds[c * 256 + tid];
            o0 = fdot2f(bch2(wv.x), bch2(hb.x), o0);
            o1 = fdot2f(bch2(wv.y), bch2(hb.y), o1);
            o2 = fdot2f(bch2(wv.z), bch2(hb.z), o2);
            o3 = fdot2f(bch2(wv.w), bch2(hb.w), o3);
        }
        // chunks 38..62: even from AGPR, odd from VGPR locals
#pragma unroll
        for (int c = 38; c < 63; c++) {
            const uint4 hb = hrd[c];
            unsigned w0, w1, w2, w3;
            asm volatile("v_accvgpr_read_b32 %0, %1" : "=v"(w0) : "a"(wa[4 * c + 0]));
            asm volatile("v_accvgpr_read_b32 %0, %1" : "=v"(w1) : "a"(wa[4 * c + 1]));
            asm volatile("v_accvgpr_read_b32 %0, %1" : "=v"(w2) : "a"(wa[4 * c + 2]));
            asm volatile("v_accvgpr_read_b32 %0, %1" : "=v"(w3) : "a"(wa[4 * c + 3]));
            s0 = fdot2f(bch2(w0), bch2(hb.x), s0);
            s1 = fdot2f(bch2(w1), bch2(hb.y), s1);
            s2 = fdot2f(bch2(w2), bch2(hb.z), s2);
            s3 = fdot2f(bch2(w3), bch2(hb.w), s3);
            const uint4 wv = ov[c - 38];
            o0 = fdot2f(bch2(wv.x), bch2(hb.x), o0);
            o1 = fdot2f(bch2(wv.y), bch2(hb.y), o1);
            o2 = fdot2f(bch2(wv.z), bch2(hb.z), o2);
            o3 = fdot2f(bch2(wv.w), bch2(hb.w), o3);
        }

        const float hv0 = tanh_fast(s0 + s1 + s2 + s3 + xp0);
        const float hv1 = tanh_fast(o0 + o1 + o2 + o3 + xp1);
        unsigned hp = 0u;
        if (tid < 250) {
            hp = __builtin_bit_cast(unsigned, h2_t{(_Float16)hv0, (_Float16)hv1});
            float2 st; st.x = hv0; st.y = hv1;
            *(float2*)(Hs + t * 512 + 2 * tid) = st;
        }
        ((unsigned*)&h16[(t + 1) & 1][0])[tid] = hp;
        __syncthreads();
    }
}

// ---------------- K3: out[t][o] = tanh(b_out[o] + sum_c Hs[t][c]*W_out[o][c])
__global__ void k3_out(const float* __restrict__ Hs, const float* __restrict__ W_out,
                       const float* __restrict__ b_out, float* __restrict__ out) {
    const int t = blockIdx.x, o = threadIdx.x;
    if (o < D_OUT) {
        const float4* wr = (const float4*)(W_out + o * H);
        const float4* hr = (const float4*)(Hs + t * 512);
        float acc = b_out[o];
#pragma unroll 5
        for (int i = 0; i < 125; i++) {
            const float4 wv = wr[i];
            const float4 hv = hr[i];
            acc = fmaf(wv.x, hv.x, acc);
            acc = fmaf(wv.y, hv.y, acc);
            acc = fmaf(wv.z, hv.z, acc);
            acc = fmaf(wv.w, hv.w, acc);
        }
        out[t * D_OUT + o] = tanh_fast(acc);
    }
}

extern "C" void kernel_launch(void* const* d_in, const int* in_sizes, int n_in,
                              void* d_out, int out_size, void* d_ws, size_t ws_size,
                              hipStream_t stream) {
    const float* x       = (const float*)d_in[0];
    const float* hidden0 = (const float*)d_in[1];
    const float* W_ih    = (const float*)d_in[2];
    const float* W_hh    = (const float*)d_in[3];
    const float* b_ih    = (const float*)d_in[4];
    const float* b_hh    = (const float*)d_in[5];
    const float* W_out   = (const float*)d_in[6];
    const float* b_out   = (const float*)d_in[7];
    float* out = (float*)d_out;

    char* ws = (char*)d_ws;
    uint4* blob_even = (uint4*)ws;                  // 63*256*16 = 258048 B
    uint4* blob_odd  = (uint4*)(ws + 258048);       // 258048 B
    float* xproj     = (float*)(ws + 516096);       // 49*512*4 = 100352 B
    float* Hs        = (float*)(ws + 616448);       // 100352 B

    k01_pack_xproj<<<188, 256, 0, stream>>>(W_hh, x, W_ih, b_ih, b_hh,
                                            blob_even, blob_odd, xproj);
    k2_scan<<<1, 256, 0, stream>>>(hidden0, blob_even, blob_odd, xproj, Hs);
    k3_out<<<STEPS, 128, 0, stream>>>(Hs, W_out, b_out, out);
}

// Round 8
// 145.609 us; speedup vs baseline: 21.0343x; 21.0343x over previous
//
#include <hip/hip_runtime.h>
#include <hip/hip_bf16.h>

#define H 500
#define D_IN 512
#define D_OUT 100
#define STEPS 49

typedef _Float16 h2_t __attribute__((ext_vector_type(2)));

#if defined(__has_builtin)
#if __has_builtin(__builtin_amdgcn_fdot2)
#define HAVE_FDOT2 1
#endif
#endif

__device__ __forceinline__ float fdot2f(h2_t a, h2_t b, float c) {
#ifdef HAVE_FDOT2
    return __builtin_amdgcn_fdot2(a, b, c, false);
#else
    return c + (float)a[0] * (float)b[0] + (float)a[1] * (float)b[1];
#endif
}
__device__ __forceinline__ h2_t bch2(unsigned u) { return __builtin_bit_cast(h2_t, u); }

__device__ __forceinline__ float tanh_fast(float x) {
    const float e = __expf(2.f * x);
    return 1.f - 2.f / (e + 1.f);
}

// Block rematerialization of an invariant-load result (kept live as asm output).
#define PINV(x) asm volatile("" : "+v"(x))

// K2 thread tid = (half = tid>>9, r = tid&511): owns cols [half*250, half*250+250)
// of row r, as 125 h2 words j=0..124. Words 0..83 -> registers (21 uint4 chunks),
// words 84..119 -> LDS (36 b32 planes), words 120..124 -> streamed from L2.

// ---------------- K01 fused: blocks 0..3 pack W_hh; blocks 4..131 compute xproj.
__global__ void k01_pack_xproj(const float* __restrict__ W_hh, const float* __restrict__ x,
                               const float* __restrict__ W_ih, const float* __restrict__ b_ih,
                               const float* __restrict__ b_hh,
                               uint4* __restrict__ blob_reg, unsigned* __restrict__ blob_lds,
                               unsigned* __restrict__ blob_str, float* __restrict__ xproj) {
    if (blockIdx.x < 4) {
        const int T = blockIdx.x * 256 + threadIdx.x;   // 0..1023
        const int r = T & 511, half = T >> 9;
        unsigned wd[125];
        if (r < H) {
            const float2* src = (const float2*)(W_hh + r * H + half * 250); // 8B aligned
#pragma unroll
            for (int j = 0; j < 125; j++) {
                const float2 f = src[j];
                wd[j] = __builtin_bit_cast(unsigned, h2_t{(_Float16)f.x, (_Float16)f.y});
            }
        } else {
#pragma unroll
            for (int j = 0; j < 125; j++) wd[j] = 0u;
        }
#pragma unroll
        for (int q = 0; q < 21; q++) {
            uint4 u; u.x = wd[4*q]; u.y = wd[4*q+1]; u.z = wd[4*q+2]; u.w = wd[4*q+3];
            blob_reg[q * 1024 + T] = u;
        }
#pragma unroll
        for (int j = 84; j < 120; j++) blob_lds[(j - 84) * 1024 + T] = wd[j];
#pragma unroll
        for (int j = 120; j < 125; j++) blob_str[(j - 120) * 1024 + T] = wd[j];
    } else {
        const int wv = threadIdx.x >> 6, lane = threadIdx.x & 63;
        const int r = (blockIdx.x - 4) * 4 + wv;       // 0..511
        if (r >= H) {                                   // hygiene: zero pad rows
            if (r < 512 && lane == 0)
                for (int t = 0; t < STEPS; t++) xproj[t * 512 + r] = 0.f;
            return;
        }
        float wr[8];
#pragma unroll
        for (int k = 0; k < 8; k++) wr[k] = W_ih[r * D_IN + k * 64 + lane];
        float p[STEPS];
#pragma unroll
        for (int t = 0; t < STEPS; t++) p[t] = 0.f;
#pragma unroll
        for (int k = 0; k < 8; k++) {
            const float* xr = x + (size_t)(k * 64 + lane) * STEPS;
#pragma unroll
            for (int t = 0; t < STEPS; t++) p[t] = fmaf(wr[k], xr[t], p[t]);
        }
#pragma unroll
        for (int t = 0; t < STEPS; t++) {
            float v = p[t];
            v += __shfl_xor(v, 32); v += __shfl_xor(v, 16); v += __shfl_xor(v, 8);
            v += __shfl_xor(v, 4);  v += __shfl_xor(v, 2);  v += __shfl_xor(v, 1);
            p[t] = v;
        }
        if (lane == 0) {
            const float b = b_ih[r] + b_hh[r];
            for (int t = 0; t < STEPS; t++) xproj[t * 512 + r] = p[t] + b;
        }
    }
}

// ---------------- K2: single-CU scan, 1024 threads = 16 waves = 4 waves/SIMD
// (128-reg budget — the allocator's comfortable regime). 84 pinned weight words
// per thread (344 KB across the block) + 36 words in LDS (147 KB) + 5 streamed
// (20 KB/step). Two threads per row; one f32 partial via LDS; 2 barriers/step.
__global__ void __launch_bounds__(1024, 4)
k2_scan(const float* __restrict__ hidden0, const uint4* __restrict__ blob_reg,
        const unsigned* __restrict__ blob_lds, const unsigned* __restrict__ blob_str,
        const float* __restrict__ xproj, float* __restrict__ Hs) {
    __shared__ unsigned wlds[36 * 1024];                  // 147456 B
    __shared__ __align__(16) _Float16 h16[2][2][256];     // 2048 B  [buf][half][i]
    __shared__ float pbuf[512];                           // 2048 B

    const int tid = threadIdx.x;            // 0..1023
    const int r = tid & 511, half = tid >> 9;

    // ---- preload: 84 words -> registers, pinned ----
    unsigned wr_[84];
#pragma unroll
    for (int q = 0; q < 21; q++) {
        const uint4 u = blob_reg[q * 1024 + tid];
        wr_[4*q+0] = u.x; PINV(wr_[4*q+0]);
        wr_[4*q+1] = u.y; PINV(wr_[4*q+1]);
        wr_[4*q+2] = u.z; PINV(wr_[4*q+2]);
        wr_[4*q+3] = u.w; PINV(wr_[4*q+3]);
    }
    // ---- preload: 36 words -> LDS ----
#pragma unroll
    for (int j = 0; j < 36; j++) wlds[j * 1024 + tid] = blob_lds[j * 1024 + tid];
    // ---- h0 ----
    if (tid < H) {
        const _Float16 hh = (_Float16)hidden0[tid];
        if (tid < 250) h16[0][0][tid] = hh; else h16[0][1][tid - 250] = hh;
    }
    __syncthreads();

#pragma unroll 1
    for (int t = 0; t < STEPS; ++t) {
        const int cur = t & 1;
        // streamed weight words (invariant; issued early, ~20 KB/step from L2)
        unsigned st0 = blob_str[0 * 1024 + tid];
        unsigned st1 = blob_str[1 * 1024 + tid];
        unsigned st2 = blob_str[2 * 1024 + tid];
        unsigned st3 = blob_str[3 * 1024 + tid];
        unsigned st4 = blob_str[4 * 1024 + tid];

        const uint4* hc = (const uint4*)&h16[cur][half][0];   // broadcast reads
        float s0 = 0.f, s1 = 0.f, s2 = 0.f, s3 = 0.f;

        // chunks 0..20: register weights (pairs 0..83)
#pragma unroll
        for (int c = 0; c < 21; c++) {
            const uint4 hb = hc[c];
            s0 = fdot2f(bch2(wr_[4*c+0]), bch2(hb.x), s0);
            s1 = fdot2f(bch2(wr_[4*c+1]), bch2(hb.y), s1);
            s2 = fdot2f(bch2(wr_[4*c+2]), bch2(hb.z), s2);
            s3 = fdot2f(bch2(wr_[4*c+3]), bch2(hb.w), s3);
        }
        // chunks 21..29: LDS weights (pairs 84..119)
#pragma unroll
        for (int c = 21; c < 30; c++) {
            const uint4 hb = hc[c];
            const int j = 4 * (c - 21);
            s0 = fdot2f(bch2(wlds[(j+0) * 1024 + tid]), bch2(hb.x), s0);
            s1 = fdot2f(bch2(wlds[(j+1) * 1024 + tid]), bch2(hb.y), s1);
            s2 = fdot2f(bch2(wlds[(j+2) * 1024 + tid]), bch2(hb.z), s2);
            s3 = fdot2f(bch2(wlds[(j+3) * 1024 + tid]), bch2(hb.w), s3);
        }
        // chunk 30 (pairs 120..123) + pair 124: streamed weights
        {
            const uint4 hb = hc[30];
            s0 = fdot2f(bch2(st0), bch2(hb.x), s0);
            s1 = fdot2f(bch2(st1), bch2(hb.y), s1);
            s2 = fdot2f(bch2(st2), bch2(hb.z), s2);
            s3 = fdot2f(bch2(st3), bch2(hb.w), s3);
            const unsigned hb4 = ((const unsigned*)&h16[cur][half][0])[124];
            s0 = fdot2f(bch2(st4), bch2(hb4), s0);
        }
        const float part = (s0 + s1) + (s2 + s3);

        if (half == 1) pbuf[r] = part;
        __syncthreads();
        if (half == 0) {
            const float xp = xproj[t * 512 + r];
            const float hv = tanh_fast(part + pbuf[r] + xp);
            if (r < H) {
                Hs[t * 512 + r] = hv;
                const _Float16 hh = (_Float16)hv;
                if (r < 250) h16[1 - cur][0][r] = hh;
                else         h16[1 - cur][1][r - 250] = hh;
            }
        }
        __syncthreads();
    }
}

// ---------------- K3: out[t][o] = tanh(b_out[o] + sum_c Hs[t][c]*W_out[o][c])
__global__ void k3_out(const float* __restrict__ Hs, const float* __restrict__ W_out,
                       const float* __restrict__ b_out, float* __restrict__ out) {
    const int t = blockIdx.x, o = threadIdx.x;
    if (o < D_OUT) {
        const float4* wr = (const float4*)(W_out + o * H);
        const float4* hr = (const float4*)(Hs + t * 512);
        float acc = b_out[o];
#pragma unroll 5
        for (int i = 0; i < 125; i++) {
            const float4 wv = wr[i];
            const float4 hv = hr[i];
            acc = fmaf(wv.x, hv.x, acc);
            acc = fmaf(wv.y, hv.y, acc);
            acc = fmaf(wv.z, hv.z, acc);
            acc = fmaf(wv.w, hv.w, acc);
        }
        out[t * D_OUT + o] = tanh_fast(acc);
    }
}

extern "C" void kernel_launch(void* const* d_in, const int* in_sizes, int n_in,
                              void* d_out, int out_size, void* d_ws, size_t ws_size,
                              hipStream_t stream) {
    const float* x       = (const float*)d_in[0];
    const float* hidden0 = (const float*)d_in[1];
    const float* W_ih    = (const float*)d_in[2];
    const float* W_hh    = (const float*)d_in[3];
    const float* b_ih    = (const float*)d_in[4];
    const float* b_hh    = (const float*)d_in[5];
    const float* W_out   = (const float*)d_in[6];
    const float* b_out   = (const float*)d_in[7];
    float* out = (float*)d_out;

    char* ws = (char*)d_ws;
    uint4*    blob_reg = (uint4*)ws;                    // 21*1024*16 = 344064
    unsigned* blob_lds = (unsigned*)(ws + 344064);      // 36*1024*4 = 147456
    unsigned* blob_str = (unsigned*)(ws + 491520);      // 5*1024*4  =  20480
    float*    xproj    = (float*)(ws + 512000);         // 49*512*4  = 100352
    float*    Hs       = (float*)(ws + 612352);         // 100352    (tot 712704)

    k01_pack_xproj<<<132, 256, 0, stream>>>(W_hh, x, W_ih, b_ih, b_hh,
                                            blob_reg, blob_lds, blob_str, xproj);
    k2_scan<<<1, 1024, 0, stream>>>(hidden0, blob_reg, blob_lds, blob_str, xproj, Hs);
    k3_out<<<STEPS, 128, 0, stream>>>(Hs, W_out, b_out, out);
}

// Round 9
// 108.635 us; speedup vs baseline: 28.1932x; 1.3403x over previous
//
#include <hip/hip_runtime.h>
#include <hip/hip_bf16.h>

#define H 500
#define D_IN 512
#define D_OUT 100
#define STEPS 49
#define NWG 4
#define RPW 125   // rows per workgroup

typedef _Float16 h2_t __attribute__((ext_vector_type(2)));

#if defined(__has_builtin)
#if __has_builtin(__builtin_amdgcn_fdot2)
#define HAVE_FDOT2 1
#endif
#endif

__device__ __forceinline__ float fdot2f(h2_t a, h2_t b, float c) {
#ifdef HAVE_FDOT2
    return __builtin_amdgcn_fdot2(a, b, c, false);
#else
    return c + (float)a[0] * (float)b[0] + (float)a[1] * (float)b[1];
#endif
}
__device__ __forceinline__ h2_t bch2(unsigned u) { return __builtin_bit_cast(h2_t, u); }
__device__ __forceinline__ unsigned pk(float a, float b) {
    return __builtin_bit_cast(unsigned, h2_t{(_Float16)a, (_Float16)b});
}
__device__ __forceinline__ float tanh_fast(float x) {
    const float e = __expf(2.f * x);
    return 1.f - 2.f / (e + 1.f);
}

// ---------------- K1: xproj[t*512+r] = b_ih[r]+b_hh[r]+sum_d seq[t][d]*W_ih[r][d]
// 125 blocks x 256 threads (4 rows per block, one per wave). seq[t][d] = x[d*49+t].
__global__ void k1_xproj(const float* __restrict__ x, const float* __restrict__ W_ih,
                         const float* __restrict__ b_ih, const float* __restrict__ b_hh,
                         float* __restrict__ xproj) {
    const int wv = threadIdx.x >> 6, lane = threadIdx.x & 63;
    const int r = blockIdx.x * 4 + wv;            // 0..499
    float wr[8];
#pragma unroll
    for (int k = 0; k < 8; k++) wr[k] = W_ih[r * D_IN + k * 64 + lane];
    float p[STEPS];
#pragma unroll
    for (int t = 0; t < STEPS; t++) p[t] = 0.f;
#pragma unroll
    for (int k = 0; k < 8; k++) {
        const float* xr = x + (size_t)(k * 64 + lane) * STEPS;
#pragma unroll
        for (int t = 0; t < STEPS; t++) p[t] = fmaf(wr[k], xr[t], p[t]);
    }
#pragma unroll
    for (int t = 0; t < STEPS; t++) {
        float v = p[t];
        v += __shfl_xor(v, 32); v += __shfl_xor(v, 16); v += __shfl_xor(v, 8);
        v += __shfl_xor(v, 4);  v += __shfl_xor(v, 2);  v += __shfl_xor(v, 1);
        p[t] = v;
    }
    if (lane == 0) {
        const float b = b_ih[r] + b_hh[r];
        for (int t = 0; t < STEPS; t++) xproj[t * 512 + r] = p[t] + b;
    }
}

// ---------------- K2: 4-WG cooperative scan, weights fully LDS-resident.
// WG g owns rows [125g, 125g+125). Thread (q = tid>>7, r = tid&127): row
// 125g+r (r<125), col slice [128q, 128q+128) as 16 uint4 (f16 pairs) in LDS.
// Sync = pure dataflow: hbuf[50][512] f32 in global, sentinel 0xFFFFFFFF
// (negative NaN; tanh output can never equal it). Writers: relaxed agent-scope
// stores of step t+1's h into hbuf[t+1]. Readers: each thread polls ONE word
// until != sentinel, stages f16 to LDS. No flags, no reset, no deadlock
// (no circular wait; 4 blocks trivially co-resident on 256 CUs).
__global__ void __launch_bounds__(512, 1)
k2_scan(const float* __restrict__ hidden0, const float* __restrict__ W_hh,
        const float* __restrict__ xproj, float* hbuf, float* __restrict__ Hs) {
    __shared__ uint4 wq[16][512];                 // 131072 B  weights
    __shared__ _Float16 hlds[2][512];             // 2048 B    h double-buffer
    __shared__ float pbuf[NWG][128];              // 2048 B    partials

    const int g = blockIdx.x, tid = threadIdx.x;
    const int q = tid >> 7, r = tid & 127;
    const int row = g * RPW + r;                  // valid when r < RPW

    // ---- one-time: load + convert this WG's weight slice into LDS ----
#pragma unroll
    for (int c = 0; c < 16; c++) {
        uint4 u = uint4{0u, 0u, 0u, 0u};
        if (r < RPW) {
            const float* rowp = W_hh + (size_t)row * H;
            const int c0 = 128 * q + 8 * c;
            if (c0 + 7 < H) {                      // fast path: 2x float4
                const float4 f0 = *(const float4*)(rowp + c0);
                const float4 f1 = *(const float4*)(rowp + c0 + 4);
                u.x = pk(f0.x, f0.y); u.y = pk(f0.z, f0.w);
                u.z = pk(f1.x, f1.y); u.w = pk(f1.z, f1.w);
            } else {                               // boundary (q==3, c>=14)
                float f[8];
#pragma unroll
                for (int e = 0; e < 8; e++) {
                    const int col = c0 + e;
                    f[e] = (col < H) ? rowp[col] : 0.f;
                }
                u.x = pk(f[0], f[1]); u.y = pk(f[2], f[3]);
                u.z = pk(f[4], f[5]); u.w = pk(f[6], f[7]);
            }
        }
        wq[c][tid] = u;
    }
    // ---- h0 + pad words (pads stay 0 forever; weights there are 0 anyway) ----
    hlds[0][tid] = (tid < H) ? (_Float16)hidden0[tid] : (_Float16)0.f;
    hlds[1][tid] = (_Float16)0.f;
    __syncthreads();

#pragma unroll 1
    for (int t = 0; t < STEPS; ++t) {
        const int cur = t & 1, nxt = cur ^ 1;
        float xp = 0.f;
        if (q == 0 && r < RPW) xp = xproj[t * 512 + row];   // early L2 load

        const uint4* hc = (const uint4*)&hlds[cur][0] + 16 * q;  // broadcast reads
        float s0 = 0.f, s1 = 0.f, s2 = 0.f, s3 = 0.f;
#pragma unroll
        for (int c = 0; c < 16; c++) {
            const uint4 wv_ = wq[c][tid];
            const uint4 hb = hc[c];
            s0 = fdot2f(bch2(wv_.x), bch2(hb.x), s0);
            s1 = fdot2f(bch2(wv_.y), bch2(hb.y), s1);
            s2 = fdot2f(bch2(wv_.z), bch2(hb.z), s2);
            s3 = fdot2f(bch2(wv_.w), bch2(hb.w), s3);
        }
        if (q != 0) pbuf[q][r] = (s0 + s1) + (s2 + s3);
        __syncthreads();

        if (q == 0 && r < RPW) {
            const float tot = (s0 + s1) + (s2 + s3)
                            + pbuf[1][r] + pbuf[2][r] + pbuf[3][r] + xp;
            const float hv = tanh_fast(tot);
            Hs[t * 512 + row] = hv;
            __hip_atomic_store(&hbuf[(t + 1) * 512 + row], hv,
                               __ATOMIC_RELAXED, __HIP_MEMORY_SCOPE_AGENT);
            hlds[nxt][row] = (_Float16)hv;         // own chunk staged locally
        }
        // stage remote words for next step (word index = tid)
        const bool own_word = (tid >= g * RPW) && (tid < g * RPW + RPW);
        if ((t + 1 < STEPS) && (tid < H) && !own_word) {
            unsigned* p = (unsigned*)&hbuf[(t + 1) * 512 + tid];
            unsigned bits_;
            do {
                bits_ = __hip_atomic_load(p, __ATOMIC_RELAXED, __HIP_MEMORY_SCOPE_AGENT);
            } while (bits_ == 0xFFFFFFFFu);
            hlds[nxt][tid] = (_Float16)__builtin_bit_cast(float, bits_);
        }
        __syncthreads();
    }
}

// ---------------- K3: out[t][o] = tanh(b_out[o] + sum_c Hs[t][c]*W_out[o][c])
__global__ void k3_out(const float* __restrict__ Hs, const float* __restrict__ W_out,
                       const float* __restrict__ b_out, float* __restrict__ out) {
    const int t = blockIdx.x, o = threadIdx.x;
    if (o < D_OUT) {
        const float4* wr = (const float4*)(W_out + o * H);
        const float4* hr = (const float4*)(Hs + t * 512);
        float acc = b_out[o];
#pragma unroll 5
        for (int i = 0; i < 125; i++) {
            const float4 wv = wr[i];
            const float4 hv = hr[i];
            acc = fmaf(wv.x, hv.x, acc);
            acc = fmaf(wv.y, hv.y, acc);
            acc = fmaf(wv.z, hv.z, acc);
            acc = fmaf(wv.w, hv.w, acc);
        }
        out[t * D_OUT + o] = tanh_fast(acc);
    }
}

extern "C" void kernel_launch(void* const* d_in, const int* in_sizes, int n_in,
                              void* d_out, int out_size, void* d_ws, size_t ws_size,
                              hipStream_t stream) {
    const float* x       = (const float*)d_in[0];
    const float* hidden0 = (const float*)d_in[1];
    const float* W_ih    = (const float*)d_in[2];
    const float* W_hh    = (const float*)d_in[3];
    const float* b_ih    = (const float*)d_in[4];
    const float* b_hh    = (const float*)d_in[5];
    const float* W_out   = (const float*)d_in[6];
    const float* b_out   = (const float*)d_in[7];
    float* out = (float*)d_out;

    char* ws = (char*)d_ws;
    float* xproj = (float*)ws;                    // 49*512*4  = 100352
    float* Hs    = (float*)(ws + 100352);         // 100352
    float* hbuf  = (float*)(ws + 200704);         // 50*512*4  = 102400

    hipMemsetAsync(hbuf, 0xFF, 50 * 512 * 4, stream);   // sentinel-init
    k1_xproj<<<125, 256, 0, stream>>>(x, W_ih, b_ih, b_hh, xproj);
    k2_scan<<<NWG, 512, 0, stream>>>(hidden0, W_hh, xproj, hbuf, Hs);
    k3_out<<<STEPS, 128, 0, stream>>>(Hs, W_out, b_out, out);
}